// Round 5
// baseline (518.269 us; speedup 1.0000x reference)
//
#include <hip/hip_runtime.h>

// Analysis filters
__device__ __constant__ float H0[8] = { 0.0322231f, -0.01260397f, -0.09921954f,  0.2978578f,
                                        0.80373875f, 0.49761867f, -0.02963553f, -0.07576571f};
__device__ __constant__ float H1[8] = { 0.07576571f, -0.02963553f, -0.49761867f, 0.80373875f,
                                       -0.2978578f, -0.09921954f,  0.01260397f,  0.0322231f};
// Synthesis filters g0 = reverse(h0), g1 = reverse(h1)
__device__ __constant__ float G0[8] = {-0.07576571f, -0.02963553f,  0.49761867f, 0.80373875f,
                                        0.2978578f,  -0.09921954f, -0.01260397f, 0.0322231f};
__device__ __constant__ float G1[8] = { 0.0322231f,   0.01260397f, -0.09921954f, -0.2978578f,
                                        0.80373875f, -0.49761867f, -0.02963553f, 0.07576571f};

// ---------------------------------------------------------------------------
// Forward DWT, 2x2-output-tiled + separable (unchanged).
// ---------------------------------------------------------------------------
template<int HIN>
__global__ __launch_bounds__(256) void fwd_dwt(const float* __restrict__ in,
                                               float* __restrict__ oLL, float* __restrict__ oLH,
                                               float* __restrict__ oHL, float* __restrict__ oHH)
{
    constexpr int OH = HIN / 2;
    constexpr int TQ = OH / 2;
    const int tid = threadIdx.x;
    const int c = tid & 63;
    const int s = blockIdx.x * 4 + (tid >> 6);
    const int j = s % TQ;
    const int i = (s / TQ) % TQ;
    const int b = s / (TQ * TQ);

    float acc[2][2][4];
#pragma unroll
    for (int a = 0; a < 2; ++a)
#pragma unroll
        for (int d = 0; d < 2; ++d)
#pragma unroll
            for (int k = 0; k < 4; ++k) acc[a][d][k] = 0.f;

    const int iw0 = 4 * j - 3;
#pragma unroll
    for (int r = 0; r < 10; ++r) {
        const int ih = 4 * i + r - 3;
        if ((unsigned)ih < (unsigned)HIN) {
            const float* row = in + ((b * HIN + ih) * HIN) * 64 + c;
            float xv[10];
#pragma unroll
            for (int v = 0; v < 10; ++v) {
                const int iw = iw0 + v;
                xv[v] = ((unsigned)iw < (unsigned)HIN) ? row[iw * 64] : 0.f;
            }
            float h00 = 0.f, h01 = 0.f, h10 = 0.f, h11 = 0.f;
#pragma unroll
            for (int v = 0; v < 8; ++v) {
                h00 += H0[v] * xv[v];
                h10 += H1[v] * xv[v];
                h01 += H0[v] * xv[v + 2];
                h11 += H1[v] * xv[v + 2];
            }
#pragma unroll
            for (int ii = 0; ii < 2; ++ii) {
                const int u = r - 2 * ii;
                if (0 <= u && u < 8) {
                    const float a0 = H0[u], a1 = H1[u];
                    acc[ii][0][0] += a0 * h00;
                    acc[ii][0][1] += a0 * h10;
                    acc[ii][0][2] += a1 * h00;
                    acc[ii][0][3] += a1 * h10;
                    acc[ii][1][0] += a0 * h01;
                    acc[ii][1][1] += a0 * h11;
                    acc[ii][1][2] += a1 * h01;
                    acc[ii][1][3] += a1 * h11;
                }
            }
        }
    }

#pragma unroll
    for (int ii = 0; ii < 2; ++ii)
#pragma unroll
        for (int jj = 0; jj < 2; ++jj) {
            const int oh = 2 * i + ii, ow = 2 * j + jj;
            const int oidx = ((b * OH + oh) * OH + ow) * 64 + c;
            oLL[oidx] = acc[ii][jj][0];
            oLH[oidx] = acc[ii][jj][1];
            oHL[oidx] = acc[ii][jj][2];
            oHH[oidx] = acc[ii][jj][3];
        }
}

// ---------------------------------------------------------------------------
// Local conv v4: LDS tile GEMM, dense 128B weight lines + more blocks.
// out[b,h,w,o] = sum_i t[b,h,w,i] * W[i,o,w,h]   (W: [C][O][Wd][Hd], h innermost)
// Block tile: 32 h x OT o x 16 b at one w. i chunked by 4.
//   W staging: float4 over h -> 8 lanes cover 128B dense per (i,o) line.
//   Thread = (hc, oq, bg): acc = (16/BGN) b x 4 o.
// Grid: (HG*64/OT, HD, nz) -> 6 blocks/CU for HD=64.
// ---------------------------------------------------------------------------
template<int HD, int OT, int HG>
__global__ __launch_bounds__(256) void local_conv_lds(
    const float* __restrict__ t0, const float* __restrict__ t1,
    const float* __restrict__ t2, const float* __restrict__ t3,
    const float* __restrict__ w0, const float* __restrict__ w1,
    const float* __restrict__ w2, const float* __restrict__ w3,
    float* __restrict__ o0, float* __restrict__ o1,
    float* __restrict__ o2, float* __restrict__ o3)
{
    constexpr int WH  = HD * HD;
    constexpr int NQ  = OT / 4;        // o-quads per tile
    constexpr int BGN = 8 / NQ;        // b-groups
    constexpr int BG  = 16 / BGN;      // b per thread
    constexpr int RSW = OT + 4;        // W row stride (16B-aligned: (OT+4)*4)
    constexpr int RSA = 20;            // act row stride
    constexpr int WL4 = OT / 8;        // W float4 loads per thread per chunk

    __shared__ __align__(16) float Wl[4][32][RSW];
    __shared__ __align__(16) float Al[4][32][RSA];

    const int z = blockIdx.z;
    const float* tin = (z == 0) ? t0 : (z == 1) ? t1 : (z == 2) ? t2 : t3;
    const float* wgt = (z == 0) ? w0 : (z == 1) ? w1 : (z == 2) ? w2 : w3;
    float*       out = (z == 0) ? o0 : (z == 1) ? o1 : (z == 2) ? o2 : o3;

    const int bx    = blockIdx.x;
    const int hg    = bx % HG;
    const int og    = bx / HG;
    const int hbase = hg * 32;
    const int w     = blockIdx.y;
    const int t     = threadIdx.x;

    // ---- staging role: W (float4 over h) ----
    int whq[WL4], wo[WL4], wi[WL4];
#pragma unroll
    for (int l = 0; l < WL4; ++l) {
        const int idx = t + 256 * l;
        whq[l] = idx & 7;
        wo[l]  = (idx >> 3) & (OT - 1);
        wi[l]  = idx >> (3 + (OT == 16 ? 4 : 3));
    }
    // ---- staging role: A (float4 over i) ----
    const int ah0 = t & 31, ab0 = t >> 5;          // + 256*l -> b += 8

    // ---- compute role ----
    const int hc = t & 31;
    const int r  = t >> 5;
    const int oq = r & (NQ - 1);
    const int bg = r / NQ;

    float4 acc4[BG];
#pragma unroll
    for (int j = 0; j < BG; ++j) acc4[j] = make_float4(0.f, 0.f, 0.f, 0.f);

    // prefetch chunk 0
    float4 wv[WL4], av[2];
#pragma unroll
    for (int l = 0; l < WL4; ++l)
        wv[l] = *(const float4*)(wgt + (size_t)(wi[l] * 64 + og * OT + wo[l]) * WH
                                 + w * HD + hbase + whq[l] * 4);
#pragma unroll
    for (int l = 0; l < 2; ++l) {
        const int b = ab0 + 8 * l;
        av[l] = *(const float4*)(tin + (size_t)((b * HD + hbase + ah0) * HD + w) * 64);
    }

    for (int chunk = 0; chunk < 16; ++chunk) {
        __syncthreads();
        // commit staged registers to LDS
#pragma unroll
        for (int l = 0; l < WL4; ++l) {
            Wl[wi[l]][whq[l] * 4 + 0][wo[l]] = wv[l].x;
            Wl[wi[l]][whq[l] * 4 + 1][wo[l]] = wv[l].y;
            Wl[wi[l]][whq[l] * 4 + 2][wo[l]] = wv[l].z;
            Wl[wi[l]][whq[l] * 4 + 3][wo[l]] = wv[l].w;
        }
#pragma unroll
        for (int l = 0; l < 2; ++l) {
            const int b = ab0 + 8 * l;
            Al[0][ah0][b] = av[l].x;
            Al[1][ah0][b] = av[l].y;
            Al[2][ah0][b] = av[l].z;
            Al[3][ah0][b] = av[l].w;
        }
        __syncthreads();

        // prefetch next chunk
        if (chunk < 15) {
            const int i0n = (chunk + 1) * 4;
#pragma unroll
            for (int l = 0; l < WL4; ++l)
                wv[l] = *(const float4*)(wgt + (size_t)((i0n + wi[l]) * 64 + og * OT + wo[l]) * WH
                                         + w * HD + hbase + whq[l] * 4);
#pragma unroll
            for (int l = 0; l < 2; ++l) {
                const int b = ab0 + 8 * l;
                av[l] = *(const float4*)(tin + (size_t)((b * HD + hbase + ah0) * HD + w) * 64 + i0n);
            }
        }

        // compute
#pragma unroll
        for (int ii = 0; ii < 4; ++ii) {
            const float4 wf = *(const float4*)&Wl[ii][hc][oq * 4];
#pragma unroll
            for (int bb = 0; bb < BG / 4; ++bb) {
                const float4 af = *(const float4*)&Al[ii][hc][bg * BG + bb * 4];
                const float* afp = (const float*)&af;
#pragma unroll
                for (int k = 0; k < 4; ++k) {
                    const float a = afp[k];
                    acc4[bb * 4 + k].x += a * wf.x;
                    acc4[bb * 4 + k].y += a * wf.y;
                    acc4[bb * 4 + k].z += a * wf.z;
                    acc4[bb * 4 + k].w += a * wf.w;
                }
            }
        }
    }

    const int obase = og * OT + oq * 4;
#pragma unroll
    for (int j = 0; j < BG; ++j) {
        const int b = bg * BG + j;
        *(float4*)(out + (size_t)((b * HD + hbase + hc) * HD + w) * 64 + obase) = acc4[j];
    }
}

// ---------------------------------------------------------------------------
// Inverse DWT, 2x2-output-tiled + separable (unchanged).
// ---------------------------------------------------------------------------
template<int HOUT>
__global__ __launch_bounds__(256) void inv_dwt(const float* __restrict__ yLL,
                                               const float* __restrict__ yLH,
                                               const float* __restrict__ yHL,
                                               const float* __restrict__ yHH,
                                               float* __restrict__ out)
{
    constexpr int HS = HOUT / 2;
    const int tid = threadIdx.x;
    const int c = tid & 63;
    const int s = blockIdx.x * 4 + (tid >> 6);
    const int j = s % HS;
    const int i = (s / HS) % HS;
    const int b = s / (HS * HS);

    float Pe[4] = {0.f, 0.f, 0.f, 0.f}, Po[4] = {0.f, 0.f, 0.f, 0.f};
    float Qe[4] = {0.f, 0.f, 0.f, 0.f}, Qo[4] = {0.f, 0.f, 0.f, 0.f};

#pragma unroll
    for (int ku = 0; ku < 4; ++ku) {
        const int m = i - 1 + ku;
        if ((unsigned)m < (unsigned)HS) {
            const float a0e = G0[1 + 2 * ku], a0o = G0[2 * ku];
            const float a1e = G1[1 + 2 * ku], a1o = G1[2 * ku];
            const int rowoff = (b * HS + m) * HS;
#pragma unroll
            for (int kv = 0; kv < 4; ++kv) {
                const int n = j - 1 + kv;
                if ((unsigned)n < (unsigned)HS) {
                    const int idx = (rowoff + n) * 64 + c;
                    const float yll = yLL[idx], ylh = yLH[idx];
                    const float yhl = yHL[idx], yhh = yHH[idx];
                    Pe[kv] += a0e * yll + a1e * yhl;
                    Po[kv] += a0o * yll + a1o * yhl;
                    Qe[kv] += a0e * ylh + a1e * yhh;
                    Qo[kv] += a0o * ylh + a1o * yhh;
                }
            }
        }
    }

    float o00 = 0.f, o01 = 0.f, o10 = 0.f, o11 = 0.f;
#pragma unroll
    for (int kv = 0; kv < 4; ++kv) {
        const float b0e = G0[1 + 2 * kv], b0o = G0[2 * kv];
        const float b1e = G1[1 + 2 * kv], b1o = G1[2 * kv];
        o00 += b0e * Pe[kv] + b1e * Qe[kv];
        o01 += b0o * Pe[kv] + b1o * Qe[kv];
        o10 += b0e * Po[kv] + b1e * Qo[kv];
        o11 += b0o * Po[kv] + b1o * Qo[kv];
    }

    const int h0 = 2 * i, w0 = 2 * j;
    const int base = ((b * HOUT + h0) * HOUT + w0) * 64 + c;
    out[base] = o00;
    out[base + 64] = o01;
    out[base + HOUT * 64] = o10;
    out[base + HOUT * 64 + 64] = o11;
}

// ---------------------------------------------------------------------------
extern "C" void kernel_launch(void* const* d_in, const int* in_sizes, int n_in,
                              void* d_out, int out_size, void* d_ws, size_t ws_size,
                              hipStream_t stream)
{
    const float* x    = (const float*)d_in[0];
    const float* wLL  = (const float*)d_in[1];
    const float* wLH0 = (const float*)d_in[2];
    const float* wHL0 = (const float*)d_in[3];
    const float* wHH0 = (const float*)d_in[4];
    const float* wLH1 = (const float*)d_in[5];
    const float* wHL1 = (const float*)d_in[6];
    const float* wHH1 = (const float*)d_in[7];
    float* out = (float*)d_out;
    float* ws  = (float*)d_ws;

    const int S0 = 16 * 64 * 64 * 64;   // level-0 subband elems
    const int S1 = 16 * 32 * 32 * 64;   // level-1 subband elems

    // d_out doubles as scratch for the 4 level-0 subbands.
    float* c0LL = out;
    float* c0LH = out + 1 * S0;
    float* c0HL = out + 2 * S0;
    float* c0HH = out + 3 * S0;

    float* c1   = ws;                      // 4*S1, later reused as r1
    float* t0   = ws + 4 * S1;             // 3*S0
    float* t1   = ws + 4 * S1 + 3 * S0;    // 3*S1
    float* yA   = ws + 7 * S1 + 3 * S0;    // S1
    float* r1   = ws;                      // S0 == 4*S1, overwrites dead c1

    // 1) level-0 forward DWT: x (16,128,128,64) -> 4x (16,64,64,64)
    fwd_dwt<128><<<16 * 32 * 32 / 4, 256, 0, stream>>>(x, c0LL, c0LH, c0HL, c0HH);

    // 2) level-1 forward DWT: cLL0 -> 4x (16,32,32,64)
    fwd_dwt<64><<<16 * 16 * 16 / 4, 256, 0, stream>>>(c0LL,
        c1 + 0 * S1, c1 + 1 * S1, c1 + 2 * S1, c1 + 3 * S1);

    // 3) local conv level-0 (Hd=Wd=64): tile 32h x 16o, grid (8, 64, 3)
    local_conv_lds<64, 16, 2><<<dim3(8, 64, 3), 256, 0, stream>>>(
        c0LH, c0HL, c0HH, nullptr,
        wLH0, wHL0, wHH0, nullptr,
        t0 + 0 * S0, t0 + 1 * S0, t0 + 2 * S0, nullptr);

    // 4) local conv level-1 (Hd=Wd=32): tile 32h x 8o, grid (8, 32, 4)
    local_conv_lds<32, 8, 1><<<dim3(8, 32, 4), 256, 0, stream>>>(
        c1 + 1 * S1, c1 + 2 * S1, c1 + 3 * S1, c1 + 0 * S1,
        wLH1, wHL1, wHH1, wLL,
        t1 + 0 * S1, t1 + 1 * S1, t1 + 2 * S1, yA);

    // 5) inverse level-1: (yA, t1) -> r1 (16,64,64,64)
    inv_dwt<64><<<16 * 32 * 32 / 4, 256, 0, stream>>>(
        yA, t1 + 0 * S1, t1 + 1 * S1, t1 + 2 * S1, r1);

    // 6) inverse level-0: (r1, t0) -> out (16,128,128,64)
    inv_dwt<128><<<16 * 64 * 64 / 4, 256, 0, stream>>>(
        r1, t0 + 0 * S0, t0 + 1 * S0, t0 + 2 * S0, out);
}

// Round 6
// 332.990 us; speedup vs baseline: 1.5564x; 1.5564x over previous
//
#include <hip/hip_runtime.h>

// Analysis filters
__device__ __constant__ float H0[8] = { 0.0322231f, -0.01260397f, -0.09921954f,  0.2978578f,
                                        0.80373875f, 0.49761867f, -0.02963553f, -0.07576571f};
__device__ __constant__ float H1[8] = { 0.07576571f, -0.02963553f, -0.49761867f, 0.80373875f,
                                       -0.2978578f, -0.09921954f,  0.01260397f,  0.0322231f};
// Synthesis filters g0 = reverse(h0), g1 = reverse(h1)
__device__ __constant__ float G0[8] = {-0.07576571f, -0.02963553f,  0.49761867f, 0.80373875f,
                                        0.2978578f,  -0.09921954f, -0.01260397f, 0.0322231f};
__device__ __constant__ float G1[8] = { 0.0322231f,   0.01260397f, -0.09921954f, -0.2978578f,
                                        0.80373875f, -0.49761867f, -0.02963553f, 0.07576571f};

// ---------------------------------------------------------------------------
// Forward DWT, 2x2-output-tiled + separable (unchanged).
// ---------------------------------------------------------------------------
template<int HIN>
__global__ __launch_bounds__(256) void fwd_dwt(const float* __restrict__ in,
                                               float* __restrict__ oLL, float* __restrict__ oLH,
                                               float* __restrict__ oHL, float* __restrict__ oHH)
{
    constexpr int OH = HIN / 2;
    constexpr int TQ = OH / 2;
    const int tid = threadIdx.x;
    const int c = tid & 63;
    const int s = blockIdx.x * 4 + (tid >> 6);
    const int j = s % TQ;
    const int i = (s / TQ) % TQ;
    const int b = s / (TQ * TQ);

    float acc[2][2][4];
#pragma unroll
    for (int a = 0; a < 2; ++a)
#pragma unroll
        for (int d = 0; d < 2; ++d)
#pragma unroll
            for (int k = 0; k < 4; ++k) acc[a][d][k] = 0.f;

    const int iw0 = 4 * j - 3;
#pragma unroll
    for (int r = 0; r < 10; ++r) {
        const int ih = 4 * i + r - 3;
        if ((unsigned)ih < (unsigned)HIN) {
            const float* row = in + ((b * HIN + ih) * HIN) * 64 + c;
            float xv[10];
#pragma unroll
            for (int v = 0; v < 10; ++v) {
                const int iw = iw0 + v;
                xv[v] = ((unsigned)iw < (unsigned)HIN) ? row[iw * 64] : 0.f;
            }
            float h00 = 0.f, h01 = 0.f, h10 = 0.f, h11 = 0.f;
#pragma unroll
            for (int v = 0; v < 8; ++v) {
                h00 += H0[v] * xv[v];
                h10 += H1[v] * xv[v];
                h01 += H0[v] * xv[v + 2];
                h11 += H1[v] * xv[v + 2];
            }
#pragma unroll
            for (int ii = 0; ii < 2; ++ii) {
                const int u = r - 2 * ii;
                if (0 <= u && u < 8) {
                    const float a0 = H0[u], a1 = H1[u];
                    acc[ii][0][0] += a0 * h00;
                    acc[ii][0][1] += a0 * h10;
                    acc[ii][0][2] += a1 * h00;
                    acc[ii][0][3] += a1 * h10;
                    acc[ii][1][0] += a0 * h01;
                    acc[ii][1][1] += a0 * h11;
                    acc[ii][1][2] += a1 * h01;
                    acc[ii][1][3] += a1 * h11;
                }
            }
        }
    }

#pragma unroll
    for (int ii = 0; ii < 2; ++ii)
#pragma unroll
        for (int jj = 0; jj < 2; ++jj) {
            const int oh = 2 * i + ii, ow = 2 * j + jj;
            const int oidx = ((b * OH + oh) * OH + ow) * 64 + c;
            oLL[oidx] = acc[ii][jj][0];
            oLH[oidx] = acc[ii][jj][1];
            oHL[oidx] = acc[ii][jj][2];
            oHH[oidx] = acc[ii][jj][3];
        }
}

// ---------------------------------------------------------------------------
// Activation transpose: t[b,h,w,i] -> A'[w][i][b][h]  (h contiguous, matching
// the weight tensor's fast axis). Both global phases are 256B-dense.
// Block = one (w, b); LDS 64 x (HD+1) tile.
// ---------------------------------------------------------------------------
template<int HD>
__global__ __launch_bounds__(256) void act_tr(const float* __restrict__ in,
                                              float* __restrict__ outp)
{
    __shared__ float Ld[64][HD + 1];
    const int w = blockIdx.x;
    const int b = blockIdx.y;
    const int t = threadIdx.x;

    {   // read: lane = i (dense 256B per (b,h,w))
        const int i = t & 63;
        const int hq = t >> 6;                    // 4 groups
#pragma unroll
        for (int s = 0; s < HD / 4; ++s) {
            const int h = hq * (HD / 4) + s;
            Ld[i][h] = in[((size_t)(b * HD + h) * HD + w) * 64 + i];
        }
    }
    __syncthreads();
    {   // write: lane = h (dense 128/256B per (w,i,b))
        const int h = t & (HD - 1);
        const int iq = t / HD;                    // 256/HD groups
        constexpr int NIQ = 256 / HD;
#pragma unroll
        for (int s = 0; s < 64 / NIQ; ++s) {
            const int i = s * NIQ + iq;
            outp[((size_t)(w * 64 + i) * 16 + b) * HD + h] = Ld[i][h];
        }
    }
}

// ---------------------------------------------------------------------------
// Local conv v5: LDS tile GEMM on transposed acts.
// out[b,h,w,o] = sum_i A'[w][i][b][h] * W[i,o,w,h]
// Block tile: 32 h x OT o x 16 b at one w; i chunked by 4.
// Every global load is a 128B-dense h-run; weights read exactly once,
// acts read once per og (og<=2 for l0).
// Thread = (hc 0..31, oo 0..3, bq 0..1): acc = 8 b x (OT/4) o.
// ---------------------------------------------------------------------------
template<int HD, int OT, int HG>
__global__ __launch_bounds__(256, 4) void local_conv_t(
    const float* __restrict__ a0, const float* __restrict__ a1,
    const float* __restrict__ a2, const float* __restrict__ a3,
    const float* __restrict__ w0, const float* __restrict__ w1,
    const float* __restrict__ w2, const float* __restrict__ w3,
    float* __restrict__ o0, float* __restrict__ o1,
    float* __restrict__ o2, float* __restrict__ o3)
{
    constexpr int WH   = HD * HD;
    constexpr int NO   = OT / 4;       // o per thread
    constexpr int WL   = OT / 8;       // W float4 loads / thread / chunk
    constexpr int LOG2OT = (OT == 32) ? 5 : 4;
    constexpr int RSW  = OT + 4;
    constexpr int RSA  = 20;

    __shared__ __align__(16) float Wl[4][32][RSW];
    __shared__ __align__(16) float Al[4][32][RSA];

    const int z = blockIdx.z;
    const float* act = (z == 0) ? a0 : (z == 1) ? a1 : (z == 2) ? a2 : a3;
    const float* wgt = (z == 0) ? w0 : (z == 1) ? w1 : (z == 2) ? w2 : w3;
    float*       out = (z == 0) ? o0 : (z == 1) ? o1 : (z == 2) ? o2 : o3;

    const int bx    = blockIdx.x;
    const int hg    = bx % HG;
    const int og    = bx / HG;
    const int hbase = hg * 32;
    const int w     = blockIdx.y;
    const int t     = threadIdx.x;

    // ---- staging roles: W (float4 over h, full 128B line per (i,o)) ----
    int whq[WL], wot[WL], wii[WL];
#pragma unroll
    for (int l = 0; l < WL; ++l) {
        const int idx = t + 256 * l;
        whq[l] = idx & 7;
        wot[l] = (idx >> 3) & (OT - 1);
        wii[l] = idx >> (3 + LOG2OT);
    }
    // ---- staging roles: A' (float4 over h, full 128B line per (i,b)) ----
    const int ahq = t & 7, ab = (t >> 3) & 15, aii0 = t >> 7;   // ii = aii0 + 2*l

    // ---- compute roles ----
    const int hc = t & 31;
    const int r  = t >> 5;
    const int oo = r & 3;
    const int bq = r >> 2;

    float4 acc4[8][NO / 4];
#pragma unroll
    for (int j = 0; j < 8; ++j)
#pragma unroll
        for (int q = 0; q < NO / 4; ++q) acc4[j][q] = make_float4(0.f, 0.f, 0.f, 0.f);

    // prefetch chunk 0
    float4 wv[WL], av[2];
#pragma unroll
    for (int l = 0; l < WL; ++l)
        wv[l] = *(const float4*)(wgt + (size_t)(wii[l] * 64 + og * OT + wot[l]) * WH
                                 + w * HD + hbase + whq[l] * 4);
#pragma unroll
    for (int l = 0; l < 2; ++l)
        av[l] = *(const float4*)(act + (size_t)((w * 64 + aii0 + 2 * l) * 16 + ab) * HD
                                 + hbase + ahq * 4);

    for (int chunk = 0; chunk < 16; ++chunk) {
        __syncthreads();
        // commit staged registers to LDS
#pragma unroll
        for (int l = 0; l < WL; ++l) {
            Wl[wii[l]][whq[l] * 4 + 0][wot[l]] = wv[l].x;
            Wl[wii[l]][whq[l] * 4 + 1][wot[l]] = wv[l].y;
            Wl[wii[l]][whq[l] * 4 + 2][wot[l]] = wv[l].z;
            Wl[wii[l]][whq[l] * 4 + 3][wot[l]] = wv[l].w;
        }
#pragma unroll
        for (int l = 0; l < 2; ++l) {
            const int ii = aii0 + 2 * l;
            Al[ii][ahq * 4 + 0][ab] = av[l].x;
            Al[ii][ahq * 4 + 1][ab] = av[l].y;
            Al[ii][ahq * 4 + 2][ab] = av[l].z;
            Al[ii][ahq * 4 + 3][ab] = av[l].w;
        }
        __syncthreads();

        // prefetch next chunk
        if (chunk < 15) {
            const int i0n = (chunk + 1) * 4;
#pragma unroll
            for (int l = 0; l < WL; ++l)
                wv[l] = *(const float4*)(wgt + (size_t)((i0n + wii[l]) * 64 + og * OT + wot[l]) * WH
                                         + w * HD + hbase + whq[l] * 4);
#pragma unroll
            for (int l = 0; l < 2; ++l)
                av[l] = *(const float4*)(act + (size_t)((w * 64 + i0n + aii0 + 2 * l) * 16 + ab) * HD
                                         + hbase + ahq * 4);
        }

        // compute
#pragma unroll
        for (int ii = 0; ii < 4; ++ii) {
            float4 wf[NO / 4];
#pragma unroll
            for (int q = 0; q < NO / 4; ++q)
                wf[q] = *(const float4*)&Wl[ii][hc][oo * NO + q * 4];
            float4 af0 = *(const float4*)&Al[ii][hc][bq * 8];
            float4 af1 = *(const float4*)&Al[ii][hc][bq * 8 + 4];
            const float* afp0 = (const float*)&af0;
            const float* afp1 = (const float*)&af1;
#pragma unroll
            for (int j = 0; j < 4; ++j) {
                const float aa = afp0[j];
#pragma unroll
                for (int q = 0; q < NO / 4; ++q) {
                    acc4[j][q].x += aa * wf[q].x;
                    acc4[j][q].y += aa * wf[q].y;
                    acc4[j][q].z += aa * wf[q].z;
                    acc4[j][q].w += aa * wf[q].w;
                }
            }
#pragma unroll
            for (int j = 0; j < 4; ++j) {
                const float aa = afp1[j];
#pragma unroll
                for (int q = 0; q < NO / 4; ++q) {
                    acc4[j + 4][q].x += aa * wf[q].x;
                    acc4[j + 4][q].y += aa * wf[q].y;
                    acc4[j + 4][q].z += aa * wf[q].z;
                    acc4[j + 4][q].w += aa * wf[q].w;
                }
            }
        }
    }

#pragma unroll
    for (int j = 0; j < 8; ++j) {
        const int b = bq * 8 + j;
        float* op = out + ((size_t)(b * HD + hbase + hc) * HD + w) * 64 + og * OT + oo * NO;
#pragma unroll
        for (int q = 0; q < NO / 4; ++q)
            *(float4*)(op + q * 4) = acc4[j][q];
    }
}

// ---------------------------------------------------------------------------
// Inverse DWT, 2x2-output-tiled + separable (unchanged).
// ---------------------------------------------------------------------------
template<int HOUT>
__global__ __launch_bounds__(256) void inv_dwt(const float* __restrict__ yLL,
                                               const float* __restrict__ yLH,
                                               const float* __restrict__ yHL,
                                               const float* __restrict__ yHH,
                                               float* __restrict__ out)
{
    constexpr int HS = HOUT / 2;
    const int tid = threadIdx.x;
    const int c = tid & 63;
    const int s = blockIdx.x * 4 + (tid >> 6);
    const int j = s % HS;
    const int i = (s / HS) % HS;
    const int b = s / (HS * HS);

    float Pe[4] = {0.f, 0.f, 0.f, 0.f}, Po[4] = {0.f, 0.f, 0.f, 0.f};
    float Qe[4] = {0.f, 0.f, 0.f, 0.f}, Qo[4] = {0.f, 0.f, 0.f, 0.f};

#pragma unroll
    for (int ku = 0; ku < 4; ++ku) {
        const int m = i - 1 + ku;
        if ((unsigned)m < (unsigned)HS) {
            const float a0e = G0[1 + 2 * ku], a0o = G0[2 * ku];
            const float a1e = G1[1 + 2 * ku], a1o = G1[2 * ku];
            const int rowoff = (b * HS + m) * HS;
#pragma unroll
            for (int kv = 0; kv < 4; ++kv) {
                const int n = j - 1 + kv;
                if ((unsigned)n < (unsigned)HS) {
                    const int idx = (rowoff + n) * 64 + c;
                    const float yll = yLL[idx], ylh = yLH[idx];
                    const float yhl = yHL[idx], yhh = yHH[idx];
                    Pe[kv] += a0e * yll + a1e * yhl;
                    Po[kv] += a0o * yll + a1o * yhl;
                    Qe[kv] += a0e * ylh + a1e * yhh;
                    Qo[kv] += a0o * ylh + a1o * yhh;
                }
            }
        }
    }

    float o00 = 0.f, o01 = 0.f, o10 = 0.f, o11 = 0.f;
#pragma unroll
    for (int kv = 0; kv < 4; ++kv) {
        const float b0e = G0[1 + 2 * kv], b0o = G0[2 * kv];
        const float b1e = G1[1 + 2 * kv], b1o = G1[2 * kv];
        o00 += b0e * Pe[kv] + b1e * Qe[kv];
        o01 += b0o * Pe[kv] + b1o * Qe[kv];
        o10 += b0e * Po[kv] + b1e * Qo[kv];
        o11 += b0o * Po[kv] + b1o * Qo[kv];
    }

    const int h0 = 2 * i, w0 = 2 * j;
    const int base = ((b * HOUT + h0) * HOUT + w0) * 64 + c;
    out[base] = o00;
    out[base + 64] = o01;
    out[base + HOUT * 64] = o10;
    out[base + HOUT * 64 + 64] = o11;
}

// ---------------------------------------------------------------------------
extern "C" void kernel_launch(void* const* d_in, const int* in_sizes, int n_in,
                              void* d_out, int out_size, void* d_ws, size_t ws_size,
                              hipStream_t stream)
{
    const float* x    = (const float*)d_in[0];
    const float* wLL  = (const float*)d_in[1];
    const float* wLH0 = (const float*)d_in[2];
    const float* wHL0 = (const float*)d_in[3];
    const float* wHH0 = (const float*)d_in[4];
    const float* wLH1 = (const float*)d_in[5];
    const float* wHL1 = (const float*)d_in[6];
    const float* wHH1 = (const float*)d_in[7];
    float* out = (float*)d_out;
    float* ws  = (float*)d_ws;

    const int S0 = 16 * 64 * 64 * 64;   // level-0 subband elems (4S1 = S0)
    const int S1 = 16 * 32 * 32 * 64;   // level-1 subband elems

    // d_out doubles as scratch: first c0{LL,LH,HL,HH}, then transposed acts.
    float* c0 = out;                    // 4*S0
    float* A0 = out;                    // 3*S0: LH',HL',HH' (reuse dead c0 slots)
    float* A1 = out + 3 * S0;           // 4*S1: LL',LH',HL',HH'

    float* c1 = ws;                     // 4*S1, later reused as r1
    float* t0 = ws + 4 * S1;            // 3*S0
    float* t1 = ws + 4 * S1 + 3 * S0;   // 3*S1
    float* yA = ws + 7 * S1 + 3 * S0;   // S1
    float* r1 = ws;                     // S0, overwrites dead c1

    // 1) level-0 forward DWT: x -> c0 (in d_out)
    fwd_dwt<128><<<16 * 32 * 32 / 4, 256, 0, stream>>>(x, c0, c0 + S0, c0 + 2 * S0, c0 + 3 * S0);

    // 2) level-1 forward DWT: c0LL -> c1 (ws)
    fwd_dwt<64><<<16 * 16 * 16 / 4, 256, 0, stream>>>(c0,
        c1 + 0 * S1, c1 + 1 * S1, c1 + 2 * S1, c1 + 3 * S1);

    // 3) transpose level-0 details into dead c0 slots (sequential: each write
    //    target is the previous transpose's (already-consumed) source).
    act_tr<64><<<dim3(64, 16), 256, 0, stream>>>(c0 + 1 * S0, A0 + 0 * S0);  // LH'
    act_tr<64><<<dim3(64, 16), 256, 0, stream>>>(c0 + 2 * S0, A0 + 1 * S0);  // HL'
    act_tr<64><<<dim3(64, 16), 256, 0, stream>>>(c0 + 3 * S0, A0 + 2 * S0);  // HH'

    // 4) transpose level-1 subbands (disjoint src/dst)
    act_tr<32><<<dim3(32, 16), 256, 0, stream>>>(c1 + 0 * S1, A1 + 0 * S1);  // LL'
    act_tr<32><<<dim3(32, 16), 256, 0, stream>>>(c1 + 1 * S1, A1 + 1 * S1);  // LH'
    act_tr<32><<<dim3(32, 16), 256, 0, stream>>>(c1 + 2 * S1, A1 + 2 * S1);  // HL'
    act_tr<32><<<dim3(32, 16), 256, 0, stream>>>(c1 + 3 * S1, A1 + 3 * S1);  // HH'

    // 5) local conv level-0: tile 32h x 32o x 16b, grid (2hg x 2og, 64w, 3z)
    local_conv_t<64, 32, 2><<<dim3(4, 64, 3), 256, 0, stream>>>(
        A0 + 0 * S0, A0 + 1 * S0, A0 + 2 * S0, nullptr,
        wLH0, wHL0, wHH0, nullptr,
        t0 + 0 * S0, t0 + 1 * S0, t0 + 2 * S0, nullptr);

    // 6) local conv level-1: tile 32h x 16o x 16b, grid (4og, 32w, 4z)
    local_conv_t<32, 16, 1><<<dim3(4, 32, 4), 256, 0, stream>>>(
        A1 + 1 * S1, A1 + 2 * S1, A1 + 3 * S1, A1 + 0 * S1,
        wLH1, wHL1, wHH1, wLL,
        t1 + 0 * S1, t1 + 1 * S1, t1 + 2 * S1, yA);

    // 7) inverse level-1: (yA, t1) -> r1
    inv_dwt<64><<<16 * 32 * 32 / 4, 256, 0, stream>>>(
        yA, t1 + 0 * S1, t1 + 1 * S1, t1 + 2 * S1, r1);

    // 8) inverse level-0: (r1, t0) -> out
    inv_dwt<128><<<16 * 64 * 64 / 4, 256, 0, stream>>>(
        r1, t0 + 0 * S0, t0 + 1 * S0, t0 + 2 * S0, out);
}